// Round 1
// baseline (253.681 us; speedup 1.0000x reference)
//
#include <hip/hip_runtime.h>

#define Bc 2
#define Sc 2048
#define Hc 2048
#define NHc 16
#define HDc 128
#define SLOTSc 16

// One block = 512 threads = 8 waves; handles 8 heads of one (b,s) row.
// grid = B*S*2. Wave w handles head n = (blockIdx&1)*8 + w.
// Lane l owns dims d = 2l, 2l+1 (float2 -> 8B/lane coalesced).
__global__ __launch_bounds__(512, 4) void stack_mem_fused(
    const float* __restrict__ hidden,     // B*S*H
    const float* __restrict__ stack,      // B*S*NH*SLOTS*HD
    const float* __restrict__ mask,       // B*S*NH*SLOTS
    const float* __restrict__ W_action,   // 48*H
    const float* __restrict__ b_action,   // 48
    const float* __restrict__ W_gate,     // HD
    const float* __restrict__ b_gate,     // 1
    const float* __restrict__ res_weight, // 1
    float* __restrict__ out,              // B*S*H
    float* __restrict__ new_stack,        // B*S*NH*SLOTS*HD
    float* __restrict__ new_mask)         // B*S*NH*SLOTS
{
    __shared__ float hid[Hc]; // 8 KB

    const int bs   = blockIdx.x >> 1;
    const int half = blockIdx.x & 1;
    const int tid  = threadIdx.x;
    const int lane = tid & 63;
    const int wave = tid >> 6;
    const int n    = half * 8 + wave;

    // ---- stage hidden row into LDS (512 thr x 16B) ----
    const float* hrow = hidden + (size_t)bs * Hc;
    ((float4*)hid)[tid] = ((const float4*)hrow)[tid];
    __syncthreads();

    // ---- action logits: rows 3n..3n+2 of W_action ----
    float p0 = 0.f, p1 = 0.f, p2 = 0.f;
    {
        const float* W0 = W_action + (size_t)(3 * n) * Hc;
        const float* W1 = W0 + Hc;
        const float* W2 = W1 + Hc;
        #pragma unroll 4
        for (int i = lane; i < Hc; i += 64) {
            float hv = hid[i];
            p0 = fmaf(hv, W0[i], p0);
            p1 = fmaf(hv, W1[i], p1);
            p2 = fmaf(hv, W2[i], p2);
        }
    }
    #pragma unroll
    for (int o = 32; o; o >>= 1) {
        p0 += __shfl_xor(p0, o, 64);
        p1 += __shfl_xor(p1, o, 64);
        p2 += __shfl_xor(p2, o, 64);
    }
    const float scale = 0.08838834764831845f; // 1/sqrt(128)
    float l0 = (p0 + b_action[3 * n + 0]) * scale;
    float l1 = (p1 + b_action[3 * n + 1]) * scale;
    float l2 = (p2 + b_action[3 * n + 2]) * scale;
    float lm = fmaxf(l0, fmaxf(l1, l2));
    float e0 = __expf(l0 - lm), e1 = __expf(l1 - lm), e2 = __expf(l2 - lm);
    float inv3 = 1.f / (e0 + e1 + e2);
    const float a_push = e0 * inv3;
    const float a_pop  = e1 * inv3;
    const float a_stay = e2 * inv3;

    // ---- per-head pointers ----
    const size_t sbase = ((size_t)bs * NHc + n) * (size_t)(SLOTSc * HDc);
    const float2* st2  = (const float2*)(stack + sbase);
    float2*       nst2 = (float2*)(new_stack + sbase);

    float2 kv = *(const float2*)(hid + n * HDc + 2 * lane);
    float2 wg = *(const float2*)(W_gate + 2 * lane);
    const float bg = b_gate[0];
    const float rw = res_weight[0];

    // ---- mask: 16 floats (one cacheline, broadcast loads) ----
    const float* mp = mask + ((size_t)bs * NHc + n) * SLOTSc;
    float m[SLOTSc];
    {
        float4 q0 = ((const float4*)mp)[0];
        float4 q1 = ((const float4*)mp)[1];
        float4 q2 = ((const float4*)mp)[2];
        float4 q3 = ((const float4*)mp)[3];
        m[0]=q0.x;  m[1]=q0.y;  m[2]=q0.z;  m[3]=q0.w;
        m[4]=q1.x;  m[5]=q1.y;  m[6]=q1.z;  m[7]=q1.w;
        m[8]=q2.x;  m[9]=q2.y;  m[10]=q2.z; m[11]=q2.w;
        m[12]=q3.x; m[13]=q3.y; m[14]=q3.z; m[15]=q3.w;
    }

    // ---- new_mask + gate bias; write new_mask ----
    float nm[SLOTSc];
    #pragma unroll
    for (int k = 0; k < SLOTSc; ++k) {
        float pm = (k == 0) ? 1.f : m[k - 1];
        float om = (k < SLOTSc - 1) ? m[k + 1] : 0.f;
        nm[k] = a_push * pm + a_pop * om + a_stay * m[k];
    }
    {
        float msel = nm[0];
        #pragma unroll
        for (int k = 1; k < SLOTSc; ++k) if (lane == k) msel = nm[k];
        if (lane < SLOTSc)
            new_mask[((size_t)bs * NHc + n) * SLOTSc + lane] = msel;
    }
    float bias[SLOTSc];
    #pragma unroll
    for (int k = 0; k < SLOTSc; ++k)
        bias[k] = bg + (1.f - nm[k]) * -1000000000.0f;

    // ---- new_stack: rolling window over slots, keep ns in regs ----
    float2 ns[SLOTSc];
    float2 prev = kv;          // push source for slot 0
    float2 cur  = st2[lane];   // stack[0]
    #pragma unroll
    for (int k = 0; k < SLOTSc; ++k) {
        float2 nxt;
        if (k < SLOTSc - 1) nxt = st2[(k + 1) * 64 + lane];
        else { nxt.x = 0.f; nxt.y = 0.f; }
        ns[k].x = a_push * prev.x + a_pop * nxt.x + a_stay * cur.x;
        ns[k].y = a_push * prev.y + a_pop * nxt.y + a_stay * cur.y;
        nst2[k * 64 + lane] = ns[k];
        prev = cur; cur = nxt;
    }

    // ---- gate scores: 16 x 64-lane butterfly reductions ----
    float gs[SLOTSc];
    #pragma unroll
    for (int k = 0; k < SLOTSc; ++k) {
        float p = ns[k].x * wg.x + ns[k].y * wg.y;
        #pragma unroll
        for (int o = 32; o; o >>= 1) p += __shfl_xor(p, o, 64);
        gs[k] = p + bias[k];
    }

    // ---- masked softmax over slots ----
    float mx = gs[0];
    #pragma unroll
    for (int k = 1; k < SLOTSc; ++k) mx = fmaxf(mx, gs[k]);
    float ssum = 0.f;
    #pragma unroll
    for (int k = 0; k < SLOTSc; ++k) { gs[k] = __expf(gs[k] - mx); ssum += gs[k]; }
    const float invs = 1.f / ssum;

    // ---- memory output + residual ----
    float2 mo; mo.x = 0.f; mo.y = 0.f;
    #pragma unroll
    for (int k = 0; k < SLOTSc; ++k) {
        float w = gs[k] * invs;
        mo.x = fmaf(w, ns[k].x, mo.x);
        mo.y = fmaf(w, ns[k].y, mo.y);
    }
    float2 ov;
    ov.x = mo.x * rw + kv.x;
    ov.y = mo.y * rw + kv.y;
    *(float2*)(out + (size_t)bs * Hc + n * HDc + 2 * lane) = ov;
}

extern "C" void kernel_launch(void* const* d_in, const int* in_sizes, int n_in,
                              void* d_out, int out_size, void* d_ws, size_t ws_size,
                              hipStream_t stream) {
    const float* hidden     = (const float*)d_in[0];
    const float* stack      = (const float*)d_in[1];
    const float* mask       = (const float*)d_in[2];
    const float* W_action   = (const float*)d_in[3];
    const float* b_action   = (const float*)d_in[4];
    const float* W_gate     = (const float*)d_in[5];
    const float* b_gate     = (const float*)d_in[6];
    const float* res_weight = (const float*)d_in[7];

    float* out       = (float*)d_out;
    float* new_stack = out + (size_t)Bc * Sc * Hc;
    float* new_mask  = new_stack + (size_t)Bc * Sc * NHc * SLOTSc * HDc;

    dim3 grid(Bc * Sc * 2);
    dim3 block(512);
    hipLaunchKernelGGL(stack_mem_fused, grid, block, 0, stream,
                       hidden, stack, mask, W_action, b_action,
                       W_gate, b_gate, res_weight,
                       out, new_stack, new_mask);
}